// Round 15
// baseline (250.878 us; speedup 1.0000x reference)
//
#include <hip/hip_runtime.h>
#include <math.h>

#define BB 2
#define TT 2304
#define CIN 256
#define C4 64
#define NHEADS 4
#define DHV 64
#define HHH 48
#define WWW 48
#define EPSV 1e-5f
#define LOG2E 1.4426950408889634f

using f16x8 = __attribute__((ext_vector_type(8))) _Float16;
using f32x4 = __attribute__((ext_vector_type(4))) float;

typedef const __attribute__((address_space(1))) unsigned int gu32;
typedef __attribute__((address_space(3))) unsigned int lu32;

// pack two f32 -> one u32 of two f16 (RTZ), type-safe via bit_cast
__device__ __forceinline__ unsigned pk2(float a, float b) {
    return __builtin_bit_cast(unsigned, __builtin_amdgcn_cvt_pkrtz(a, b));
}

__device__ __forceinline__ f32x4 MFMA(f16x8 a, f16x8 b, f32x4 c) {
    return __builtin_amdgcn_mfma_f32_16x16x32_f16(a, b, c, 0, 0, 0);
}

// workspace layout (byte offsets)
#define WSB_IDENT 0u          // [BB][CIN][TT] f32      4718592
#define WSB_RT16  4718592u    // [4][BB][TT][64] f16    2359296
#define WSB_YS    8257536u    // [3][BB][C4][TT] f32    3538944
#define WSB_QH    11796480u   // [32][TT][64] f16       9437184  (log2e-scaled)
#define WSB_KH    21233664u   // [32][TT][64] f16       9437184
#define WSB_VT    30670848u   // [32][64][TT] f16       9437184  (V transposed)
#define WSB_OC16  40108032u   // [BB][TT][1024] f16     9437184
#define WSB_W16   49545216u   // wq,wk,wv,wout,wci,pw f16 (380928 elems)
#define WSB_X16   50307072u   // [BB*TT][256] f16       2359296

// ---------------------------------------------------------------------------
// f32 -> f16 conversion. Units of 8 f32: wq/wk/wv 2048 each, wout 32768,
// wci 8192, pw 512, x 147456 -> total 195072 = 762 blocks x 256 exactly.
// ---------------------------------------------------------------------------
__global__ __launch_bounds__(256) void wcvt(
    const float* __restrict__ wq, const float* __restrict__ wk,
    const float* __restrict__ wv, const float* __restrict__ wo,
    const float* __restrict__ wc, const float* __restrict__ pw,
    const float* __restrict__ xx,
    _Float16* __restrict__ w16, _Float16* __restrict__ x16)
{
    const int i = blockIdx.x * 256 + threadIdx.x;
    const float* s; _Float16* d; int off;
    if (i < 2048)       { s = wq; d = w16;           off = i; }
    else if (i < 4096)  { s = wk; d = w16 + 16384;   off = i - 2048; }
    else if (i < 6144)  { s = wv; d = w16 + 32768;   off = i - 4096; }
    else if (i < 38912) { s = wo; d = w16 + 49152;   off = i - 6144; }
    else if (i < 47104) { s = wc; d = w16 + 311296;  off = i - 38912; }
    else if (i < 47616) { s = pw; d = w16 + 376832;  off = i - 47104; }
    else                { s = xx; d = x16;           off = i - 47616; }
    float4 a = ((const float4*)s)[off * 2];
    float4 b = ((const float4*)s)[off * 2 + 1];
    uint4 u;
    u.x = pk2(a.x, a.y); u.y = pk2(a.z, a.w);
    u.z = pk2(b.x, b.y); u.w = pk2(b.z, b.w);
    ((uint4*)d)[off] = u;
}

// ---------------------------------------------------------------------------
// conv_in (1x1, K=256) + BN1 as f16 MFMA -> identity f32 (ch-major) and
// rt16 scale0 (tok-major, blocks with o0==0 only).
// ---------------------------------------------------------------------------
__global__ __launch_bounds__(256) void cin_mfma(
    const _Float16* __restrict__ x16, const _Float16* __restrict__ wci16,
    const float* __restrict__ bg, const float* __restrict__ bb,
    const float* __restrict__ bm, const float* __restrict__ bv,
    float* __restrict__ ident, _Float16* __restrict__ rt16)
{
    const int tid = threadIdx.x;
    const int wv = tid >> 6;
    const int lane = tid & 63;
    const int g = lane >> 4, ln = lane & 15;
    const int m0 = blockIdx.x * 128 + wv * 32;
    const int o0 = blockIdx.y * 64;
    const int b = m0 / TT;
    const int t0 = m0 - b * TT;

    f32x4 acc[2][4] = {};
    for (int ks = 0; ks < 8; ++ks) {
        f16x8 a0 = *(const f16x8*)(x16 + ((size_t)(m0 + ln)) * 256 + ks * 32 + g * 8);
        f16x8 a1 = *(const f16x8*)(x16 + ((size_t)(m0 + 16 + ln)) * 256 + ks * 32 + g * 8);
        #pragma unroll
        for (int oi = 0; oi < 4; ++oi) {
            f16x8 bf = *(const f16x8*)(wci16 + ((size_t)(o0 + oi * 16 + ln)) * 256 + ks * 32 + g * 8);
            acc[0][oi] = MFMA(a0, bf, acc[0][oi]);
            acc[1][oi] = MFMA(a1, bf, acc[1][oi]);
        }
    }
    #pragma unroll
    for (int oi = 0; oi < 4; ++oi) {
        const int o = o0 + oi * 16 + ln;
        const float inv = bg[o] * rsqrtf(bv[o] + EPSV);
        const float bet = bb[o] - bm[o] * inv;
        #pragma unroll
        for (int mi = 0; mi < 2; ++mi)
            #pragma unroll
            for (int r = 0; r < 4; ++r) {
                const int t = t0 + mi * 16 + g * 4 + r;
                const float val = acc[mi][oi][r] * inv + bet;
                ident[((size_t)(b * CIN + o)) * TT + t] = val;
                if (o0 == 0) rt16[((size_t)(b * TT + t)) * C4 + o] = (_Float16)val;
            }
    }
}

// ---------------------------------------------------------------------------
// FUSED depthwise 3x3 + pointwise 1x1 + BN2 (one kernel per scale).
// Block = 64 tokens. Phase 1: each thread computes dw for 8 consecutive
// channels at one token (2 strips), b128-writes f16 to dwls[64][72]
// (stride 144B -> bank-balanced 8 lanes/quad for both write and read).
// Phase 2: 4-wave f16 MFMA 64t x 64o x K64 from dwls; BN2 epilogue writes
// rt16[s] (f16 tok-major) + ys[s-1] (f32 ch-major, float4).
// ---------------------------------------------------------------------------
__global__ __launch_bounds__(256) void dwpw(
    const float* __restrict__ ident, const float* __restrict__ ysprev,
    const float* __restrict__ dww, const _Float16* __restrict__ pw16,
    _Float16* __restrict__ rt16, float* __restrict__ ysout,
    const float* __restrict__ bg, const float* __restrict__ bb,
    const float* __restrict__ bm, const float* __restrict__ bv,
    int s)
{
    __shared__ __align__(16) _Float16 dwls[64][72];
    const int tid = threadIdx.x;
    const int m0 = blockIdx.x * 64;
    const int b = m0 / TT;
    const int t0 = m0 - b * TT;

    // ---- phase 1: depthwise 3x3 ----
    {
        const int t_l = tid & 63;
        const int t = t0 + t_l;
        const int h = t / WWW, wc_ = t - h * WWW;
        const float* p1 = ident + ((size_t)(b * CIN + s * C4)) * TT;
        const float* p2 = ysprev ? ysprev + ((size_t)(b * C4)) * TT : nullptr;
        #pragma unroll
        for (int u = 0; u < 2; ++u) {
            const int c0 = ((tid >> 6) + u * 4) * 8;
            float acc[8] = {};
            #pragma unroll
            for (int kh = 0; kh < 3; ++kh) {
                const int hh2 = h + kh - 1;
                if (hh2 < 0 || hh2 >= HHH) continue;
                #pragma unroll
                for (int kw = 0; kw < 3; ++kw) {
                    const int ww2 = wc_ + kw - 1;
                    if (ww2 < 0 || ww2 >= WWW) continue;
                    const int t2 = hh2 * WWW + ww2;
                    #pragma unroll
                    for (int j = 0; j < 8; ++j) {
                        float v = p1[(size_t)(c0 + j) * TT + t2];
                        if (p2) v += p2[(size_t)(c0 + j) * TT + t2];
                        acc[j] = fmaf(v, dww[(c0 + j) * 9 + kh * 3 + kw], acc[j]);
                    }
                }
            }
            uint4 u4;
            u4.x = pk2(acc[0], acc[1]); u4.y = pk2(acc[2], acc[3]);
            u4.z = pk2(acc[4], acc[5]); u4.w = pk2(acc[6], acc[7]);
            *(uint4*)&dwls[t_l][c0] = u4;
        }
    }
    __syncthreads();

    // ---- phase 2: pointwise MFMA + BN2 ----
    const int wv = tid >> 6;
    const int lane = tid & 63;
    const int g = lane >> 4, ln = lane & 15;
    const int tw = wv * 16;
    f32x4 acc2[4] = {};
    #pragma unroll
    for (int ks = 0; ks < 2; ++ks) {
        f16x8 a = *(const f16x8*)&dwls[tw + ln][ks * 32 + g * 8];
        #pragma unroll
        for (int oi = 0; oi < 4; ++oi) {
            f16x8 bf = *(const f16x8*)(pw16 + ((size_t)(oi * 16 + ln)) * 64 + ks * 32 + g * 8);
            acc2[oi] = MFMA(a, bf, acc2[oi]);
        }
    }
    #pragma unroll
    for (int oi = 0; oi < 4; ++oi) {
        const int o = oi * 16 + ln;
        const float inv = bg[o] * rsqrtf(bv[o] + EPSV);
        const float bet = bb[o] - bm[o] * inv;
        const int tt = t0 + tw + g * 4;
        float4 vals;
        #pragma unroll
        for (int r = 0; r < 4; ++r) {
            const float val = acc2[oi][r] * inv + bet;
            rt16[(((size_t)s * BB + b) * TT + tt + r) * C4 + o] = (_Float16)val;
            ((float*)&vals)[r] = val;
        }
        *(float4*)&ysout[((size_t)(b * C4 + o)) * TT + tt] = vals;
    }
}

// ---------------------------------------------------------------------------
// q/k/v projection, f16 MFMA (unchanged).
// ---------------------------------------------------------------------------
__global__ __launch_bounds__(256) void qkv_mfma(
    const _Float16* __restrict__ rt16, const _Float16* __restrict__ w16,
    _Float16* __restrict__ qh, _Float16* __restrict__ kh, _Float16* __restrict__ vt)
{
    const int tid = threadIdx.x;
    const int wv = tid >> 6;
    const int lane = tid & 63;
    const int g = lane >> 4, ln = lane & 15;
    const int z = blockIdx.z;
    const _Float16* W = w16 + z * 16384;
    const int m0 = blockIdx.x * 128 + wv * 32;
    const int o0 = blockIdx.y * 32;
    const int s = m0 / (BB * TT);
    const int rem = m0 - s * (BB * TT);
    const int b = rem / TT;
    const int t0 = rem - b * TT;
    const int h = o0 >> 6;
    const int dbase = (o0 & 63);
    const int combo = (s * BB + b) * NHEADS + h;

    if (z < 2) {
        f16x8 a[2][2], bf[2][2];
        #pragma unroll
        for (int mi = 0; mi < 2; ++mi)
            #pragma unroll
            for (int ks = 0; ks < 2; ++ks)
                a[mi][ks] = *(const f16x8*)(rt16 + ((size_t)(m0 + mi * 16 + ln)) * 64 + ks * 32 + g * 8);
        #pragma unroll
        for (int oi = 0; oi < 2; ++oi)
            #pragma unroll
            for (int ks = 0; ks < 2; ++ks)
                bf[oi][ks] = *(const f16x8*)(W + ((size_t)(o0 + oi * 16 + ln)) * 64 + ks * 32 + g * 8);
        f32x4 acc[2][2] = {};
        #pragma unroll
        for (int ks = 0; ks < 2; ++ks)
            #pragma unroll
            for (int mi = 0; mi < 2; ++mi)
                #pragma unroll
                for (int oi = 0; oi < 2; ++oi)
                    acc[mi][oi] = MFMA(a[mi][ks], bf[oi][ks], acc[mi][oi]);
        _Float16* dst = (z == 0) ? qh : kh;
        const float sc = (z == 0) ? LOG2E : 1.f;
        #pragma unroll
        for (int mi = 0; mi < 2; ++mi)
            #pragma unroll
            for (int oi = 0; oi < 2; ++oi) {
                const int d = dbase + oi * 16 + ln;
                #pragma unroll
                for (int r = 0; r < 4; ++r) {
                    const int t = t0 + mi * 16 + g * 4 + r;
                    dst[((size_t)combo * TT + t) * DHV + d] = (_Float16)(acc[mi][oi][r] * sc);
                }
            }
    } else {
        f16x8 a[2][2], bf[2][2];
        #pragma unroll
        for (int oi = 0; oi < 2; ++oi)
            #pragma unroll
            for (int ks = 0; ks < 2; ++ks)
                a[oi][ks] = *(const f16x8*)(W + ((size_t)(o0 + oi * 16 + ln)) * 64 + ks * 32 + g * 8);
        #pragma unroll
        for (int ti = 0; ti < 2; ++ti)
            #pragma unroll
            for (int ks = 0; ks < 2; ++ks)
                bf[ti][ks] = *(const f16x8*)(rt16 + ((size_t)(m0 + ti * 16 + ln)) * 64 + ks * 32 + g * 8);
        f32x4 acc[2][2] = {};
        #pragma unroll
        for (int ks = 0; ks < 2; ++ks)
            #pragma unroll
            for (int oi = 0; oi < 2; ++oi)
                #pragma unroll
                for (int ti = 0; ti < 2; ++ti)
                    acc[oi][ti] = MFMA(a[oi][ks], bf[ti][ks], acc[oi][ti]);
        #pragma unroll
        for (int oi = 0; oi < 2; ++oi)
            #pragma unroll
            for (int ti = 0; ti < 2; ++ti) {
                const int t = t0 + ti * 16 + ln;
                #pragma unroll
                for (int r = 0; r < 4; ++r) {
                    const int d = dbase + oi * 16 + g * 4 + r;
                    vt[((size_t)combo * DHV + d) * TT + t] = (_Float16)acc[oi][ti][r];
                }
            }
    }
}

// ---------------------------------------------------------------------------
// Output projection, f16 MFMA (unchanged).
// ---------------------------------------------------------------------------
__global__ __launch_bounds__(256) void out_mfma(
    const _Float16* __restrict__ oc16, const _Float16* __restrict__ wout16,
    float* __restrict__ out)
{
    const int tid = threadIdx.x;
    const int wv = tid >> 6;
    const int lane = tid & 63;
    const int g = lane >> 4, ln = lane & 15;
    const int m0 = blockIdx.x * 64 + wv * 16;
    const int o0 = blockIdx.y * 32;
    f32x4 acc[2] = {};
    for (int k0 = 0; k0 < 1024; k0 += 32) {
        f16x8 a = *(const f16x8*)(oc16 + ((size_t)(m0 + ln)) * 1024 + k0 + g * 8);
        #pragma unroll
        for (int oi = 0; oi < 2; ++oi) {
            f16x8 bf = *(const f16x8*)(wout16 + ((size_t)(o0 + oi * 16 + ln)) * 1024 + k0 + g * 8);
            acc[oi] = MFMA(a, bf, acc[oi]);
        }
    }
    #pragma unroll
    for (int oi = 0; oi < 2; ++oi)
        #pragma unroll
        for (int r = 0; r < 4; ++r)
            out[((size_t)(m0 + g * 4 + r)) * CIN + o0 + oi * 16 + ln] = acc[oi][r];
}

// ---------------------------------------------------------------------------
// f16 MFMA flash attention. vs round 14:
//  - Plds shrunk [4][16][88] -> [4][16][64] XOR-swizzled (same sw as Kls;
//    writer/reader share row ln -> same bijection). LDS total = 40960 exactly
//    -> 4 blocks/CU with launch_bounds(256,4) (was 3; occupancy +33%).
//  - deferred lrun: per-lane partial sums, cross-group reduce ONCE in the
//    epilogue -> removes 2 shfl_xor (~240cyc LDS latency) per iteration.
//  - exact defer-max: skip corr/O-rescale when __all(mx <= mrun) (THR=0,
//    bit-exact: corr would be 1).
//  - 2x-unrolled body with literal buffer index -> swizzled addrs hoisted.
// ---------------------------------------------------------------------------
__global__ __launch_bounds__(256, 4) void attn_mfma(
    const _Float16* __restrict__ qh, const _Float16* __restrict__ kh,
    const _Float16* __restrict__ vt, _Float16* __restrict__ oc16)
{
    __shared__ __align__(16) _Float16 Kls[2][4096];   // [64 rows][64 f16] swizzled
    __shared__ __align__(16) _Float16 Vls[2][4096];   // [64 d][64 k] swizzled
    __shared__ __align__(16) _Float16 Plds[4][16][64]; // swizzled, wave-private

    const int tid = threadIdx.x;
    const int wv = tid >> 6;
    const int lane = tid & 63;
    const int g = lane >> 4, ln = lane & 15;
    const int bid = blockIdx.x;
    const int xcd = bid & 7, slot = bid >> 3;          // 1152 = 8 x 144
    const int combo = (xcd << 2) | (slot / 36);
    const int q0 = (slot % 36) * 64 + wv * 16;
    const _Float16* Q = qh + (size_t)combo * TT * DHV;
    const _Float16* K = kh + (size_t)combo * TT * DHV;
    const _Float16* V = vt + (size_t)combo * DHV * TT;

    const int srow = wv * 16 + (lane >> 3);
    const int scol = ((lane & 7) ^ ((lane >> 3) & 7)) * 8;   // source-side swizzle
    const int sw = (ln & 7) << 3;                            // read-side XOR (elems)

    f16x8 bq[2];
    #pragma unroll
    for (int k0 = 0; k0 < 2; ++k0)
        bq[k0] = *(const f16x8*)(Q + ((size_t)(q0 + ln)) * DHV + k0 * 32 + g * 8);

    f32x4 O[4] = {};
    float mrun = -1e30f, lpart = 0.f;

    // prologue: stage K(0), V(0) -> buf 0
    #pragma unroll
    for (int j = 0; j < 2; ++j)
        __builtin_amdgcn_global_load_lds(
            (gu32*)(K + (size_t)(srow + j * 8) * DHV + scol),
            (lu32*)&Kls[0][(wv * 2 + j) * 512], 16, 0, 0);
    #pragma unroll
    for (int j = 0; j < 2; ++j)
        __builtin_amdgcn_global_load_lds(
            (gu32*)(V + (size_t)(srow + j * 8) * TT + 0 + scol),
            (lu32*)&Vls[0][(wv * 2 + j) * 512], 16, 0, 0);
    __syncthreads();

#define ATTN_STEP(IT, CUR)                                                         \
    {                                                                              \
        const int kn = ((IT) + 1 < 36) ? ((IT) + 1) * 64 : 0;                      \
        _Pragma("unroll")                                                          \
        for (int j = 0; j < 2; ++j)                                                \
            __builtin_amdgcn_global_load_lds(                                      \
                (gu32*)(K + (size_t)(kn + srow + j * 8) * DHV + scol),             \
                (lu32*)&Kls[(CUR) ^ 1][(wv * 2 + j) * 512], 16, 0, 0);             \
        _Pragma("unroll")                                                          \
        for (int j = 0; j < 2; ++j)                                                \
            __builtin_amdgcn_global_load_lds(                                      \
                (gu32*)(V + (size_t)(srow + j * 8) * TT + kn + scol),              \
                (lu32*)&Vls[(CUR) ^ 1][(wv * 2 + j) * 512], 16, 0, 0);             \
        f32x4 S[4] = {};                                                           \
        __builtin_amdgcn_s_setprio(1);                                             \
        _Pragma("unroll")                                                          \
        for (int m = 0; m < 4; ++m) {                                              \
            f16x8 ak0 = *(const f16x8*)&Kls[CUR][(((m * 16 + ln) * 64) + g * 8) ^ sw];      \
            f16x8 ak1 = *(const f16x8*)&Kls[CUR][(((m * 16 + ln) * 64) + 32 + g * 8) ^ sw]; \
            S[m] = MFMA(ak0, bq[0], S[m]);                                         \
            S[m] = MFMA(ak1, bq[1], S[m]);                                         \
        }                                                                          \
        __builtin_amdgcn_s_setprio(0);                                             \
        float a0 = fmaxf(fmaxf(S[0][0], S[0][1]), fmaxf(S[0][2], S[0][3]));        \
        float a1 = fmaxf(fmaxf(S[1][0], S[1][1]), fmaxf(S[1][2], S[1][3]));        \
        float a2 = fmaxf(fmaxf(S[2][0], S[2][1]), fmaxf(S[2][2], S[2][3]));        \
        float a3 = fmaxf(fmaxf(S[3][0], S[3][1]), fmaxf(S[3][2], S[3][3]));        \
        float mx = fmaxf(fmaxf(a0, a1), fmaxf(a2, a3));                            \
        mx = fmaxf(mx, __shfl_xor(mx, 16));                                        \
        mx = fmaxf(mx, __shfl_xor(mx, 32));                                        \
        const bool upd = !__all(mx <= mrun);                                       \
        float corr = 1.f;                                                          \
        if (upd) {                                                                 \
            const float mnew = fmaxf(mrun, mx);                                    \
            corr = exp2f(mrun - mnew);                                             \
            mrun = mnew;                                                           \
        }                                                                          \
        float psm = 0.f;                                                           \
        _Pragma("unroll")                                                          \
        for (int m = 0; m < 4; ++m) {                                              \
            _Pragma("unroll")                                                      \
            for (int r = 0; r < 4; ++r) S[m][r] = exp2f(S[m][r] - mrun);           \
            psm += (S[m][0] + S[m][1]) + (S[m][2] + S[m][3]);                      \
            uint2 u;                                                               \
            u.x = pk2(S[m][0], S[m][1]);                                           \
            u.y = pk2(S[m][2], S[m][3]);                                           \
            *(uint2*)&Plds[wv][ln][(m * 16 + g * 4) ^ sw] = u;                     \
        }                                                                          \
        if (upd) {                                                                 \
            lpart = lpart * corr + psm;                                            \
            _Pragma("unroll")                                                      \
            for (int m = 0; m < 4; ++m) O[m] *= corr;                              \
        } else {                                                                   \
            lpart += psm;                                                          \
        }                                                                          \
        f16x8 bp0 = *(const f16x8*)&Plds[wv][ln][(g * 8) ^ sw];                    \
        f16x8 bp1 = *(const f16x8*)&Plds[wv][ln][(32 + g * 8) ^ sw];               \
        __builtin_amdgcn_s_setprio(1);                                             \
        _Pragma("unroll")                                                          \
        for (int m = 0; m < 4; ++m) {                                              \
            f16x8 av0 = *(const f16x8*)&Vls[CUR][(((m * 16 + ln) * 64) + g * 8) ^ sw];      \
            f16x8 av1 = *(const f16x8*)&Vls[CUR][(((m * 16 + ln) * 64) + 32 + g * 8) ^ sw]; \
            O[m] = MFMA(av0, bp0, O[m]);                                           \
            O[m] = MFMA(av1, bp1, O[m]);                                           \
        }                                                                          \
        __builtin_amdgcn_s_setprio(0);                                             \
        __syncthreads();                                                           \
    }

    for (int it = 0; it < 36; it += 2) {
        ATTN_STEP(it, 0)
        ATTN_STEP(it + 1, 1)
    }
#undef ATTN_STEP

    // ---- epilogue: reduce deferred l across g-groups, write 16 q-rows ----
    float l = lpart;
    l += __shfl_xor(l, 16);
    l += __shfl_xor(l, 32);
    const float inv = 1.f / l;
    const int s_ = combo >> 3, b_ = (combo >> 2) & 1, h_ = combo & 3;
    const int tok = q0 + ln;
    #pragma unroll
    for (int m = 0; m < 4; ++m) {
        uint2 u;
        u.x = pk2(O[m][0] * inv, O[m][1] * inv);
        u.y = pk2(O[m][2] * inv, O[m][3] * inv);
        *(uint2*)&oc16[((size_t)(b_ * TT + tok)) * 1024 + s_ * 256 + h_ * 64 + m * 16 + g * 4] = u;
    }
}

// ---------------------------------------------------------------------------
extern "C" void kernel_launch(void* const* d_in, const int* in_sizes, int n_in,
                              void* d_out, int out_size, void* d_ws, size_t ws_size,
                              hipStream_t stream)
{
    const float* x    = (const float*)d_in[0];
    const float* wci  = (const float*)d_in[1];
    const float* b1g  = (const float*)d_in[2];
    const float* b1b  = (const float*)d_in[3];
    const float* b1m  = (const float*)d_in[4];
    const float* b1v  = (const float*)d_in[5];
    const float* dww  = (const float*)d_in[6];
    const float* pww  = (const float*)d_in[7];
    const float* b2g  = (const float*)d_in[8];
    const float* b2b  = (const float*)d_in[9];
    const float* b2m  = (const float*)d_in[10];
    const float* b2v  = (const float*)d_in[11];
    const float* Wq   = (const float*)d_in[12];
    const float* Wk   = (const float*)d_in[13];
    const float* Wv   = (const float*)d_in[14];
    const float* Wout = (const float*)d_in[15];

    char* wsb = (char*)d_ws;
    float*     ident = (float*)(wsb + WSB_IDENT);
    _Float16*  rt16  = (_Float16*)(wsb + WSB_RT16);
    float*     ysch  = (float*)(wsb + WSB_YS);
    _Float16*  qh    = (_Float16*)(wsb + WSB_QH);
    _Float16*  khp   = (_Float16*)(wsb + WSB_KH);
    _Float16*  vtp   = (_Float16*)(wsb + WSB_VT);
    _Float16*  oc16  = (_Float16*)(wsb + WSB_OC16);
    _Float16*  w16   = (_Float16*)(wsb + WSB_W16);
    _Float16*  x16   = (_Float16*)(wsb + WSB_X16);
    float*     outp  = (float*)d_out;

    // 0) f32->f16: wq, wk, wv, wout, wci, pw, x (195072 units = 762 x 256)
    wcvt<<<dim3(762), 256, 0, stream>>>(Wq, Wk, Wv, Wout, wci, pww, x, w16, x16);

    // 1) conv_in (1x1) + BN1, f16 MFMA -> identity f32 + rt16 scale0
    cin_mfma<<<dim3(36, 4), 256, 0, stream>>>(
        x16, w16 + 311296, b1g, b1b, b1m, b1v, ident, rt16);

    // 2) Res2Net chain: FUSED dw3x3 + pw + BN2, scales 1..3 (sequential)
    for (int s = 1; s <= 3; ++s) {
        const float* yp = (s == 1) ? nullptr : (ysch + (size_t)(s - 2) * BB * C4 * TT);
        dwpw<<<dim3(BB * TT / 64), 256, 0, stream>>>(
            ident, yp, dww, w16 + 376832, rt16,
            ysch + (size_t)(s - 1) * BB * C4 * TT,
            b2g, b2b, b2m, b2v, s);
    }

    // 3) q/k/v projections, f16 MFMA -> qh (log2e-scaled), kh, vt (V^T)
    qkv_mfma<<<dim3(144, 8, 3), 256, 0, stream>>>(rt16, w16, qh, khp, vtp);

    // 4) f16 MFMA flash attention -> oc16 f16
    attn_mfma<<<dim3(36 * 32), 256, 0, stream>>>(qh, khp, vtp, oc16);

    // 5) output projection, f16 MFMA -> d_out f32
    out_mfma<<<dim3(72, 8), 256, 0, stream>>>(oc16, w16 + 49152, outp);
}

// Round 16
// 206.554 us; speedup vs baseline: 1.2146x; 1.2146x over previous
//
#include <hip/hip_runtime.h>
#include <math.h>

#define BB 2
#define TT 2304
#define CIN 256
#define C4 64
#define NHEADS 4
#define DHV 64
#define HHH 48
#define WWW 48
#define EPSV 1e-5f
#define LOG2E 1.4426950408889634f

using f16x8 = __attribute__((ext_vector_type(8))) _Float16;
using f32x4 = __attribute__((ext_vector_type(4))) float;

typedef const __attribute__((address_space(1))) unsigned int gu32;
typedef __attribute__((address_space(3))) unsigned int lu32;

// pack two f32 -> one u32 of two f16 (RTZ), type-safe via bit_cast
__device__ __forceinline__ unsigned pk2(float a, float b) {
    return __builtin_bit_cast(unsigned, __builtin_amdgcn_cvt_pkrtz(a, b));
}

__device__ __forceinline__ f32x4 MFMA(f16x8 a, f16x8 b, f32x4 c) {
    return __builtin_amdgcn_mfma_f32_16x16x32_f16(a, b, c, 0, 0, 0);
}

// workspace layout (byte offsets)
#define WSB_IDENT 0u          // [BB][CIN][TT] f32      4718592
#define WSB_RT16  4718592u    // [4][BB][TT][64] f16    2359296
#define WSB_DWT   7077888u    // [C4][BB*TT] f32        1179648
#define WSB_YS    8257536u    // [3][BB][C4][TT] f32    3538944
#define WSB_QH    11796480u   // [32][TT][64] f16       9437184  (log2e-scaled)
#define WSB_KH    21233664u   // [32][TT][64] f16       9437184
#define WSB_VT    30670848u   // [32][64][TT] f16       9437184  (V transposed)
#define WSB_OC16  40108032u   // [BB][TT][1024] f16     9437184
#define WSB_W16   49545216u   // wq,wk,wv(3x16384) wout(262144) wci(65536) f16
#define WSB_X16   50298880u   // [BB*TT][256] f16       2359296

// ---------------------------------------------------------------------------
// f32 -> f16 conversion. Units of 8 f32: wq/wk/wv 2048 each, wout 32768,
// wci 8192, x 147456 -> total 194560 = 760 blocks x 256 exactly.
// ---------------------------------------------------------------------------
__global__ __launch_bounds__(256) void wcvt(
    const float* __restrict__ wq, const float* __restrict__ wk,
    const float* __restrict__ wv, const float* __restrict__ wo,
    const float* __restrict__ wc, const float* __restrict__ xx,
    _Float16* __restrict__ w16, _Float16* __restrict__ x16)
{
    const int i = blockIdx.x * 256 + threadIdx.x;
    const float* s; _Float16* d; int off;
    if (i < 2048)       { s = wq; d = w16;           off = i; }
    else if (i < 4096)  { s = wk; d = w16 + 16384;   off = i - 2048; }
    else if (i < 6144)  { s = wv; d = w16 + 32768;   off = i - 4096; }
    else if (i < 38912) { s = wo; d = w16 + 49152;   off = i - 6144; }
    else if (i < 47104) { s = wc; d = w16 + 311296;  off = i - 38912; }
    else                { s = xx; d = x16;           off = i - 47104; }
    float4 a = ((const float4*)s)[off * 2];
    float4 b = ((const float4*)s)[off * 2 + 1];
    uint4 u;
    u.x = pk2(a.x, a.y); u.y = pk2(a.z, a.w);
    u.z = pk2(b.x, b.y); u.w = pk2(b.z, b.w);
    ((uint4*)d)[off] = u;
}

// ---------------------------------------------------------------------------
// conv_in (1x1, K=256) + BN1 as f16 MFMA -> identity f32 (ch-major) and
// rt16 scale0 (tok-major, blocks with o0==0 only).
// ---------------------------------------------------------------------------
__global__ __launch_bounds__(256) void cin_mfma(
    const _Float16* __restrict__ x16, const _Float16* __restrict__ wci16,
    const float* __restrict__ bg, const float* __restrict__ bb,
    const float* __restrict__ bm, const float* __restrict__ bv,
    float* __restrict__ ident, _Float16* __restrict__ rt16)
{
    const int tid = threadIdx.x;
    const int wv = tid >> 6;
    const int lane = tid & 63;
    const int g = lane >> 4, ln = lane & 15;
    const int m0 = blockIdx.x * 128 + wv * 32;
    const int o0 = blockIdx.y * 64;
    const int b = m0 / TT;
    const int t0 = m0 - b * TT;

    f32x4 acc[2][4] = {};
    for (int ks = 0; ks < 8; ++ks) {
        f16x8 a0 = *(const f16x8*)(x16 + ((size_t)(m0 + ln)) * 256 + ks * 32 + g * 8);
        f16x8 a1 = *(const f16x8*)(x16 + ((size_t)(m0 + 16 + ln)) * 256 + ks * 32 + g * 8);
        #pragma unroll
        for (int oi = 0; oi < 4; ++oi) {
            f16x8 bf = *(const f16x8*)(wci16 + ((size_t)(o0 + oi * 16 + ln)) * 256 + ks * 32 + g * 8);
            acc[0][oi] = MFMA(a0, bf, acc[0][oi]);
            acc[1][oi] = MFMA(a1, bf, acc[1][oi]);
        }
    }
    #pragma unroll
    for (int oi = 0; oi < 4; ++oi) {
        const int o = o0 + oi * 16 + ln;
        const float inv = bg[o] * rsqrtf(bv[o] + EPSV);
        const float bet = bb[o] - bm[o] * inv;
        #pragma unroll
        for (int mi = 0; mi < 2; ++mi)
            #pragma unroll
            for (int r = 0; r < 4; ++r) {
                const int t = t0 + mi * 16 + g * 4 + r;
                const float val = acc[mi][oi][r] * inv + bet;
                ident[((size_t)(b * CIN + o)) * TT + t] = val;
                if (o0 == 0) rt16[((size_t)(b * TT + t)) * C4 + o] = (_Float16)val;
            }
    }
}

// ---------------------------------------------------------------------------
// Depthwise 3x3 SAME, output col-major [C4][BB*TT]. 1152 blocks (full chip).
// ---------------------------------------------------------------------------
__global__ __launch_bounds__(256) void dw3x3(
    const float* __restrict__ ident, const float* __restrict__ ysprev,
    const float* __restrict__ dww, float* __restrict__ dwt, int s)
{
    const int g = blockIdx.x * 256 + threadIdx.x;
    const int t = g % TT;
    const int c = (g / TT) & (C4 - 1);
    const int b = g / (TT * C4);
    const int h = t / WWW, w = t % WWW;
    const float* p1 = ident + ((size_t)(b * CIN + s * C4 + c)) * TT;
    const float* p2 = ysprev ? (ysprev + ((size_t)(b * C4 + c)) * TT) : nullptr;
    float acc = 0.f;
    #pragma unroll
    for (int kh = 0; kh < 3; ++kh) {
        const int hh2 = h + kh - 1;
        if (hh2 < 0 || hh2 >= HHH) continue;
        #pragma unroll
        for (int kw = 0; kw < 3; ++kw) {
            const int ww2 = w + kw - 1;
            if (ww2 < 0 || ww2 >= WWW) continue;
            const int t2 = hh2 * WWW + ww2;
            float v = p1[t2];
            if (p2) v += p2[t2];
            acc = fmaf(v, dww[c * 9 + kh * 3 + kw], acc);
        }
    }
    dwt[(size_t)c * (BB * TT) + b * TT + t] = acc;
}

// ---------------------------------------------------------------------------
// Pointwise 1x1 (K=64) + BN2, fp32: A [K][M] col-major (dwt), W [N][K].
// -> rt16[scale] (f16 tok-major) + ys_ch[scale-1] (f32 ch-major).
// ---------------------------------------------------------------------------
__global__ __launch_bounds__(256) void pw_gemm(
    const float* __restrict__ A, const float* __restrict__ W,
    float* __restrict__ out, float* __restrict__ out2,
    const float* __restrict__ bg, const float* __restrict__ bb,
    const float* __restrict__ bm, const float* __restrict__ bv,
    int scale_s)
{
    __shared__ __align__(16) float As[16][68];
    __shared__ __align__(16) float Ws[16][68];
    const int tid = threadIdx.x;
    const int m0 = blockIdx.x * 64;
    const int tm = tid & 15, tn = tid >> 4;
    float acc[4][4] = {};
    for (int k0 = 0; k0 < C4; k0 += 16) {
        __syncthreads();
        {
            const int kk = tid >> 4, mc = tid & 15;
            float4 a4 = *(const float4*)&A[(size_t)(k0 + kk) * (BB * TT) + m0 + mc * 4];
            *(float4*)&As[kk][mc * 4] = a4;
        }
        {
            const int lr = tid >> 2, lc = tid & 3;
            float4 w4 = *(const float4*)&W[(size_t)lr * C4 + k0 + lc * 4];
            Ws[lc * 4 + 0][lr] = w4.x; Ws[lc * 4 + 1][lr] = w4.y;
            Ws[lc * 4 + 2][lr] = w4.z; Ws[lc * 4 + 3][lr] = w4.w;
        }
        __syncthreads();
        #pragma unroll
        for (int kk = 0; kk < 16; ++kk) {
            float4 af = *(const float4*)&As[kk][tm * 4];
            float4 wf = *(const float4*)&Ws[kk][tn * 4];
            float av[4] = {af.x, af.y, af.z, af.w};
            float wv[4] = {wf.x, wf.y, wf.z, wf.w};
            #pragma unroll
            for (int i = 0; i < 4; ++i)
                #pragma unroll
                for (int j = 0; j < 4; ++j)
                    acc[i][j] = fmaf(av[i], wv[j], acc[i][j]);
        }
    }
    _Float16* rt16 = (_Float16*)out;
    #pragma unroll
    for (int j = 0; j < 4; ++j) {
        const int o = tn * 4 + j;
        const float inv = bg[o] * rsqrtf(bv[o] + EPSV);
        const float bet = bb[o] - bm[o] * inv;
        #pragma unroll
        for (int i = 0; i < 4; ++i) {
            const int m = m0 + tm * 4 + i;
            const int b = m / TT, t = m % TT;
            const float val = acc[i][j] * inv + bet;
            rt16[(((size_t)scale_s * BB + b) * TT + t) * C4 + o] = (_Float16)val;
            out2[(((size_t)(scale_s - 1) * BB + b) * C4 + o) * TT + t] = val;
        }
    }
}

// ---------------------------------------------------------------------------
// q/k/v projection, f16 MFMA (unchanged).
// ---------------------------------------------------------------------------
__global__ __launch_bounds__(256) void qkv_mfma(
    const _Float16* __restrict__ rt16, const _Float16* __restrict__ w16,
    _Float16* __restrict__ qh, _Float16* __restrict__ kh, _Float16* __restrict__ vt)
{
    const int tid = threadIdx.x;
    const int wv = tid >> 6;
    const int lane = tid & 63;
    const int g = lane >> 4, ln = lane & 15;
    const int z = blockIdx.z;
    const _Float16* W = w16 + z * 16384;
    const int m0 = blockIdx.x * 128 + wv * 32;
    const int o0 = blockIdx.y * 32;
    const int s = m0 / (BB * TT);
    const int rem = m0 - s * (BB * TT);
    const int b = rem / TT;
    const int t0 = rem - b * TT;
    const int h = o0 >> 6;
    const int dbase = (o0 & 63);
    const int combo = (s * BB + b) * NHEADS + h;

    if (z < 2) {
        f16x8 a[2][2], bf[2][2];
        #pragma unroll
        for (int mi = 0; mi < 2; ++mi)
            #pragma unroll
            for (int ks = 0; ks < 2; ++ks)
                a[mi][ks] = *(const f16x8*)(rt16 + ((size_t)(m0 + mi * 16 + ln)) * 64 + ks * 32 + g * 8);
        #pragma unroll
        for (int oi = 0; oi < 2; ++oi)
            #pragma unroll
            for (int ks = 0; ks < 2; ++ks)
                bf[oi][ks] = *(const f16x8*)(W + ((size_t)(o0 + oi * 16 + ln)) * 64 + ks * 32 + g * 8);
        f32x4 acc[2][2] = {};
        #pragma unroll
        for (int ks = 0; ks < 2; ++ks)
            #pragma unroll
            for (int mi = 0; mi < 2; ++mi)
                #pragma unroll
                for (int oi = 0; oi < 2; ++oi)
                    acc[mi][oi] = MFMA(a[mi][ks], bf[oi][ks], acc[mi][oi]);
        _Float16* dst = (z == 0) ? qh : kh;
        const float sc = (z == 0) ? LOG2E : 1.f;
        #pragma unroll
        for (int mi = 0; mi < 2; ++mi)
            #pragma unroll
            for (int oi = 0; oi < 2; ++oi) {
                const int d = dbase + oi * 16 + ln;
                #pragma unroll
                for (int r = 0; r < 4; ++r) {
                    const int t = t0 + mi * 16 + g * 4 + r;
                    dst[((size_t)combo * TT + t) * DHV + d] = (_Float16)(acc[mi][oi][r] * sc);
                }
            }
    } else {
        f16x8 a[2][2], bf[2][2];
        #pragma unroll
        for (int oi = 0; oi < 2; ++oi)
            #pragma unroll
            for (int ks = 0; ks < 2; ++ks)
                a[oi][ks] = *(const f16x8*)(W + ((size_t)(o0 + oi * 16 + ln)) * 64 + ks * 32 + g * 8);
        #pragma unroll
        for (int ti = 0; ti < 2; ++ti)
            #pragma unroll
            for (int ks = 0; ks < 2; ++ks)
                bf[ti][ks] = *(const f16x8*)(rt16 + ((size_t)(m0 + ti * 16 + ln)) * 64 + ks * 32 + g * 8);
        f32x4 acc[2][2] = {};
        #pragma unroll
        for (int ks = 0; ks < 2; ++ks)
            #pragma unroll
            for (int oi = 0; oi < 2; ++oi)
                #pragma unroll
                for (int ti = 0; ti < 2; ++ti)
                    acc[oi][ti] = MFMA(a[oi][ks], bf[ti][ks], acc[oi][ti]);
        #pragma unroll
        for (int oi = 0; oi < 2; ++oi)
            #pragma unroll
            for (int ti = 0; ti < 2; ++ti) {
                const int t = t0 + ti * 16 + ln;
                #pragma unroll
                for (int r = 0; r < 4; ++r) {
                    const int d = dbase + oi * 16 + g * 4 + r;
                    vt[((size_t)combo * DHV + d) * TT + t] = (_Float16)acc[oi][ti][r];
                }
            }
    }
}

// ---------------------------------------------------------------------------
// Output projection, f16 MFMA (unchanged).
// ---------------------------------------------------------------------------
__global__ __launch_bounds__(256) void out_mfma(
    const _Float16* __restrict__ oc16, const _Float16* __restrict__ wout16,
    float* __restrict__ out)
{
    const int tid = threadIdx.x;
    const int wv = tid >> 6;
    const int lane = tid & 63;
    const int g = lane >> 4, ln = lane & 15;
    const int m0 = blockIdx.x * 64 + wv * 16;
    const int o0 = blockIdx.y * 32;
    f32x4 acc[2] = {};
    for (int k0 = 0; k0 < 1024; k0 += 32) {
        f16x8 a = *(const f16x8*)(oc16 + ((size_t)(m0 + ln)) * 1024 + k0 + g * 8);
        #pragma unroll
        for (int oi = 0; oi < 2; ++oi) {
            f16x8 bf = *(const f16x8*)(wout16 + ((size_t)(o0 + oi * 16 + ln)) * 1024 + k0 + g * 8);
            acc[oi] = MFMA(a, bf, acc[oi]);
        }
    }
    #pragma unroll
    for (int oi = 0; oi < 2; ++oi)
        #pragma unroll
        for (int r = 0; r < 4; ++r)
            out[((size_t)(m0 + g * 4 + r)) * CIN + o0 + oi * 16 + ln] = acc[oi][r];
}

// ---------------------------------------------------------------------------
// f16 MFMA flash attention (round-15 version, kept):
//  - Kls/Vls double-buffered via global_load_lds, ONE barrier per tile.
//  - Plds [4][16][64] XOR-swizzled; LDS total 40960 -> 4 blocks/CU.
//  - deferred lrun (epilogue reduce), exact defer-max (skip corr when
//    __all(mx<=mrun)), 2x-unrolled body with literal buffer index.
// ---------------------------------------------------------------------------
__global__ __launch_bounds__(256, 4) void attn_mfma(
    const _Float16* __restrict__ qh, const _Float16* __restrict__ kh,
    const _Float16* __restrict__ vt, _Float16* __restrict__ oc16)
{
    __shared__ __align__(16) _Float16 Kls[2][4096];   // [64 rows][64 f16] swizzled
    __shared__ __align__(16) _Float16 Vls[2][4096];   // [64 d][64 k] swizzled
    __shared__ __align__(16) _Float16 Plds[4][16][64]; // swizzled, wave-private

    const int tid = threadIdx.x;
    const int wv = tid >> 6;
    const int lane = tid & 63;
    const int g = lane >> 4, ln = lane & 15;
    const int bid = blockIdx.x;
    const int xcd = bid & 7, slot = bid >> 3;          // 1152 = 8 x 144
    const int combo = (xcd << 2) | (slot / 36);
    const int q0 = (slot % 36) * 64 + wv * 16;
    const _Float16* Q = qh + (size_t)combo * TT * DHV;
    const _Float16* K = kh + (size_t)combo * TT * DHV;
    const _Float16* V = vt + (size_t)combo * DHV * TT;

    const int srow = wv * 16 + (lane >> 3);
    const int scol = ((lane & 7) ^ ((lane >> 3) & 7)) * 8;   // source-side swizzle
    const int sw = (ln & 7) << 3;                            // read-side XOR (elems)

    f16x8 bq[2];
    #pragma unroll
    for (int k0 = 0; k0 < 2; ++k0)
        bq[k0] = *(const f16x8*)(Q + ((size_t)(q0 + ln)) * DHV + k0 * 32 + g * 8);

    f32x4 O[4] = {};
    float mrun = -1e30f, lpart = 0.f;

    // prologue: stage K(0), V(0) -> buf 0
    #pragma unroll
    for (int j = 0; j < 2; ++j)
        __builtin_amdgcn_global_load_lds(
            (gu32*)(K + (size_t)(srow + j * 8) * DHV + scol),
            (lu32*)&Kls[0][(wv * 2 + j) * 512], 16, 0, 0);
    #pragma unroll
    for (int j = 0; j < 2; ++j)
        __builtin_amdgcn_global_load_lds(
            (gu32*)(V + (size_t)(srow + j * 8) * TT + 0 + scol),
            (lu32*)&Vls[0][(wv * 2 + j) * 512], 16, 0, 0);
    __syncthreads();

#define ATTN_STEP(IT, CUR)                                                         \
    {                                                                              \
        const int kn = ((IT) + 1 < 36) ? ((IT) + 1) * 64 : 0;                      \
        _Pragma("unroll")                                                          \
        for (int j = 0; j < 2; ++j)                                                \
            __builtin_amdgcn_global_load_lds(                                      \
                (gu32*)(K + (size_t)(kn + srow + j * 8) * DHV + scol),             \
                (lu32*)&Kls[(CUR) ^ 1][(wv * 2 + j) * 512], 16, 0, 0);             \
        _Pragma("unroll")                                                          \
        for (int j = 0; j < 2; ++j)                                                \
            __builtin_amdgcn_global_load_lds(                                      \
                (gu32*)(V + (size_t)(srow + j * 8) * TT + kn + scol),              \
                (lu32*)&Vls[(CUR) ^ 1][(wv * 2 + j) * 512], 16, 0, 0);             \
        f32x4 S[4] = {};                                                           \
        __builtin_amdgcn_s_setprio(1);                                             \
        _Pragma("unroll")                                                          \
        for (int m = 0; m < 4; ++m) {                                              \
            f16x8 ak0 = *(const f16x8*)&Kls[CUR][(((m * 16 + ln) * 64) + g * 8) ^ sw];      \
            f16x8 ak1 = *(const f16x8*)&Kls[CUR][(((m * 16 + ln) * 64) + 32 + g * 8) ^ sw]; \
            S[m] = MFMA(ak0, bq[0], S[m]);                                         \
            S[m] = MFMA(ak1, bq[1], S[m]);                                         \
        }                                                                          \
        __builtin_amdgcn_s_setprio(0);                                             \
        float a0 = fmaxf(fmaxf(S[0][0], S[0][1]), fmaxf(S[0][2], S[0][3]));        \
        float a1 = fmaxf(fmaxf(S[1][0], S[1][1]), fmaxf(S[1][2], S[1][3]));        \
        float a2 = fmaxf(fmaxf(S[2][0], S[2][1]), fmaxf(S[2][2], S[2][3]));        \
        float a3 = fmaxf(fmaxf(S[3][0], S[3][1]), fmaxf(S[3][2], S[3][3]));        \
        float mx = fmaxf(fmaxf(a0, a1), fmaxf(a2, a3));                            \
        mx = fmaxf(mx, __shfl_xor(mx, 16));                                        \
        mx = fmaxf(mx, __shfl_xor(mx, 32));                                        \
        const bool upd = !__all(mx <= mrun);                                       \
        float corr = 1.f;                                                          \
        if (upd) {                                                                 \
            const float mnew = fmaxf(mrun, mx);                                    \
            corr = exp2f(mrun - mnew);                                             \
            mrun = mnew;                                                           \
        }                                                                          \
        float psm = 0.f;                                                           \
        _Pragma("unroll")                                                          \
        for (int m = 0; m < 4; ++m) {                                              \
            _Pragma("unroll")                                                      \
            for (int r = 0; r < 4; ++r) S[m][r] = exp2f(S[m][r] - mrun);           \
            psm += (S[m][0] + S[m][1]) + (S[m][2] + S[m][3]);                      \
            uint2 u;                                                               \
            u.x = pk2(S[m][0], S[m][1]);                                           \
            u.y = pk2(S[m][2], S[m][3]);                                           \
            *(uint2*)&Plds[wv][ln][(m * 16 + g * 4) ^ sw] = u;                     \
        }                                                                          \
        if (upd) {                                                                 \
            lpart = lpart * corr + psm;                                            \
            _Pragma("unroll")                                                      \
            for (int m = 0; m < 4; ++m) O[m] *= corr;                              \
        } else {                                                                   \
            lpart += psm;                                                          \
        }                                                                          \
        f16x8 bp0 = *(const f16x8*)&Plds[wv][ln][(g * 8) ^ sw];                    \
        f16x8 bp1 = *(const f16x8*)&Plds[wv][ln][(32 + g * 8) ^ sw];               \
        __builtin_amdgcn_s_setprio(1);                                             \
        _Pragma("unroll")                                                          \
        for (int m = 0; m < 4; ++m) {                                              \
            f16x8 av0 = *(const f16x8*)&Vls[CUR][(((m * 16 + ln) * 64) + g * 8) ^ sw];      \
            f16x8 av1 = *(const f16x8*)&Vls[CUR][(((m * 16 + ln) * 64) + 32 + g * 8) ^ sw]; \
            O[m] = MFMA(av0, bp0, O[m]);                                           \
            O[m] = MFMA(av1, bp1, O[m]);                                           \
        }                                                                          \
        __builtin_amdgcn_s_setprio(0);                                             \
        __syncthreads();                                                           \
    }

    for (int it = 0; it < 36; it += 2) {
        ATTN_STEP(it, 0)
        ATTN_STEP(it + 1, 1)
    }
#undef ATTN_STEP

    // ---- epilogue: reduce deferred l across g-groups, write 16 q-rows ----
    float l = lpart;
    l += __shfl_xor(l, 16);
    l += __shfl_xor(l, 32);
    const float inv = 1.f / l;
    const int s_ = combo >> 3, b_ = (combo >> 2) & 1, h_ = combo & 3;
    const int tok = q0 + ln;
    #pragma unroll
    for (int m = 0; m < 4; ++m) {
        uint2 u;
        u.x = pk2(O[m][0] * inv, O[m][1] * inv);
        u.y = pk2(O[m][2] * inv, O[m][3] * inv);
        *(uint2*)&oc16[((size_t)(b_ * TT + tok)) * 1024 + s_ * 256 + h_ * 64 + m * 16 + g * 4] = u;
    }
}

// ---------------------------------------------------------------------------
extern "C" void kernel_launch(void* const* d_in, const int* in_sizes, int n_in,
                              void* d_out, int out_size, void* d_ws, size_t ws_size,
                              hipStream_t stream)
{
    const float* x    = (const float*)d_in[0];
    const float* wci  = (const float*)d_in[1];
    const float* b1g  = (const float*)d_in[2];
    const float* b1b  = (const float*)d_in[3];
    const float* b1m  = (const float*)d_in[4];
    const float* b1v  = (const float*)d_in[5];
    const float* dww  = (const float*)d_in[6];
    const float* pww  = (const float*)d_in[7];
    const float* b2g  = (const float*)d_in[8];
    const float* b2b  = (const float*)d_in[9];
    const float* b2m  = (const float*)d_in[10];
    const float* b2v  = (const float*)d_in[11];
    const float* Wq   = (const float*)d_in[12];
    const float* Wk   = (const float*)d_in[13];
    const float* Wv   = (const float*)d_in[14];
    const float* Wout = (const float*)d_in[15];

    char* wsb = (char*)d_ws;
    float*     ident = (float*)(wsb + WSB_IDENT);
    _Float16*  rt16  = (_Float16*)(wsb + WSB_RT16);
    float*     dwt   = (float*)(wsb + WSB_DWT);
    float*     ysch  = (float*)(wsb + WSB_YS);
    _Float16*  qh    = (_Float16*)(wsb + WSB_QH);
    _Float16*  khp   = (_Float16*)(wsb + WSB_KH);
    _Float16*  vtp   = (_Float16*)(wsb + WSB_VT);
    _Float16*  oc16  = (_Float16*)(wsb + WSB_OC16);
    _Float16*  w16   = (_Float16*)(wsb + WSB_W16);
    _Float16*  x16   = (_Float16*)(wsb + WSB_X16);
    float*     outp  = (float*)d_out;

    // 0) f32->f16: wq, wk, wv, wout, wci, x (194560 units = 760 x 256)
    wcvt<<<dim3(760), 256, 0, stream>>>(Wq, Wk, Wv, Wout, wci, x, w16, x16);

    // 1) conv_in (1x1) + BN1, f16 MFMA -> identity f32 + rt16 scale0
    cin_mfma<<<dim3(36, 4), 256, 0, stream>>>(
        x16, w16 + 311296, b1g, b1b, b1m, b1v, ident, rt16);

    // 2) Res2Net chain: dw3x3 (1152 blocks) -> pw + BN2, scales 1..3
    for (int s = 1; s <= 3; ++s) {
        const float* yp = (s == 1) ? nullptr : (ysch + (size_t)(s - 2) * BB * C4 * TT);
        dw3x3<<<dim3(BB * C4 * TT / 256), 256, 0, stream>>>(ident, yp, dww, dwt, s);
        pw_gemm<<<dim3(BB * TT / 64), 256, 0, stream>>>(
            dwt, pww, (float*)rt16, ysch, b2g, b2b, b2m, b2v, s);
    }

    // 3) q/k/v projections, f16 MFMA -> qh (log2e-scaled), kh, vt (V^T)
    qkv_mfma<<<dim3(144, 8, 3), 256, 0, stream>>>(rt16, w16, qh, khp, vtp);

    // 4) f16 MFMA flash attention -> oc16 f16
    attn_mfma<<<dim3(36 * 32), 256, 0, stream>>>(qh, khp, vtp, oc16);

    // 5) output projection, f16 MFMA -> d_out f32
    out_mfma<<<dim3(72, 8), 256, 0, stream>>>(oc16, w16 + 49152, outp);
}